// Round 1
// baseline (10046.067 us; speedup 1.0000x reference)
//
#include <hip/hip_runtime.h>

#define DI __device__ __forceinline__

typedef __attribute__((ext_vector_type(8))) short s16x8;
typedef __attribute__((ext_vector_type(4))) float f32x4;

constexpr int BB = 32, TT = 512, NH = 1024, NG = 4096, KX = 512, KT = 1536;
constexpr int NT0 = 2048, NT1 = 512;

// d_out element offsets (f32): dec0, dec1, h_t, c_t
constexpr size_t OFF_DEC1 = (size_t)BB * TT * NT0;             // 33554432
constexpr size_t OFF_H    = OFF_DEC1 + (size_t)BB * TT * NT1;  // 41943040
constexpr size_t OFF_C    = OFF_H + (size_t)BB * NH;           // 41975808

// workspace byte offsets (all 256-aligned)
constexpr size_t WS_WCAT = 0;                                   // bf16 [4096][1536] = Wih||Whh
constexpr size_t WS_WD0  = WS_WCAT + (size_t)NG * KT * 2;       // bf16 [2048][1024]
constexpr size_t WS_WD1  = WS_WD0 + (size_t)NT0 * NH * 2;       // bf16 [512][1024]
constexpr size_t WS_XE   = WS_WD1 + (size_t)NT1 * NH * 2;       // bf16 [T][32][512] embedded x
constexpr size_t WS_HSX  = WS_XE + (size_t)TT * BB * KX * 2;    // bf16 [T+1][32][1024] h history
constexpr size_t WS_BIAS = WS_HSX + (size_t)(TT + 1) * BB * NH * 2; // f32 [4096] b_ih+b_hh
constexpr size_t WS_CNT  = WS_BIAS + (size_t)NG * 4;            // u32 barrier counter

DI unsigned short f2bf(float f) {  // round-to-nearest-even f32 -> bf16
  unsigned u = __float_as_uint(f);
  u += 0x7fffu + ((u >> 16) & 1u);
  return (unsigned short)(u >> 16);
}

// ---------------- prep kernels ----------------

__global__ __launch_bounds__(256) void k_wcat(const float* __restrict__ Wih,
                                              const float* __restrict__ Whh,
                                              unsigned short* __restrict__ Wcat) {
  int n = blockIdx.x;  // 0..4095
  for (int k = threadIdx.x; k < KT; k += 256) {
    float v = (k < KX) ? Wih[(size_t)n * KX + k] : Whh[(size_t)n * NH + (k - KX)];
    Wcat[(size_t)n * KT + k] = f2bf(v);
  }
}

__global__ __launch_bounds__(256) void k_wd(const float* __restrict__ Wd0,
                                            const float* __restrict__ Wd1,
                                            unsigned short* __restrict__ Wd0b,
                                            unsigned short* __restrict__ Wd1b) {
  int bid = blockIdx.x;  // 0..2559
  const float* src;
  unsigned short* dst;
  if (bid < NT0) { src = Wd0 + (size_t)bid * NH; dst = Wd0b + (size_t)bid * NH; }
  else           { src = Wd1 + (size_t)(bid - NT0) * NH; dst = Wd1b + (size_t)(bid - NT0) * NH; }
  for (int k = threadIdx.x; k < NH; k += 256) dst[k] = f2bf(src[k]);
}

__global__ __launch_bounds__(256) void k_misc(const float* __restrict__ bih,
                                              const float* __restrict__ bhh,
                                              const float* __restrict__ h0,
                                              float* __restrict__ bias,
                                              unsigned short* __restrict__ hsx,
                                              unsigned* __restrict__ cnt) {
  int i = blockIdx.x * 256 + threadIdx.x;
  if (i < NG) bias[i] = bih[i] + bhh[i];
  else if (i < NG + BB * NH) { int j = i - NG; hsx[j] = f2bf(h0[j]); }
  else if (i == NG + BB * NH) *cnt = 0u;
}

__global__ __launch_bounds__(64) void k_embed(const int* __restrict__ tok0,
                                              const int* __restrict__ tok1,
                                              const float* __restrict__ emb0,
                                              const float* __restrict__ emb1,
                                              unsigned short* __restrict__ xe) {
  int r = blockIdx.x;        // r = t*32 + b
  int t = r >> 5, b = r & 31;
  int i = threadIdx.x;       // 0..63
  int a0 = tok0[b * TT + t], a1 = tok1[b * TT + t];
  const float4* e0 = (const float4*)(emb0 + (size_t)a0 * 256);
  const float4* e1 = (const float4*)(emb1 + (size_t)a1 * 256);
  float4 v0 = e0[i], v1 = e1[i];
  unsigned short* dst = xe + (size_t)r * KX;
  dst[i * 4 + 0] = f2bf(v0.x); dst[i * 4 + 1] = f2bf(v0.y);
  dst[i * 4 + 2] = f2bf(v0.z); dst[i * 4 + 3] = f2bf(v0.w);
  dst[256 + i * 4 + 0] = f2bf(v1.x); dst[256 + i * 4 + 1] = f2bf(v1.y);
  dst[256 + i * 4 + 2] = f2bf(v1.z); dst[256 + i * 4 + 3] = f2bf(v1.w);
}

// ---------------- persistent LSTM ----------------

DI void grid_barrier(unsigned* cnt, unsigned target) {
  __syncthreads();  // drains each wave's global stores (vmcnt(0) before s_barrier)
  if (threadIdx.x == 0) {
    __threadfence();  // agent release: L2 writeback so other XCDs see hsx stores
    __hip_atomic_fetch_add(cnt, 1u, __ATOMIC_RELAXED, __HIP_MEMORY_SCOPE_AGENT);
    while (__hip_atomic_load(cnt, __ATOMIC_ACQUIRE, __HIP_MEMORY_SCOPE_AGENT) < target)
      __builtin_amdgcn_s_sleep(2);
  }
  __syncthreads();
}

// grid: 64 blocks x 512 threads. Block owns 16 hidden units (hidx = blk*16 + 0..15).
// Waves: w = (gate g = w>>1) x (M-half mh = w&1). c kept in registers across steps.
__global__ __launch_bounds__(512) void k_lstm(const unsigned short* __restrict__ xe,
                                              const unsigned short* __restrict__ Wcat,
                                              const float* __restrict__ bias,
                                              unsigned short* __restrict__ hsx,
                                              const float* __restrict__ c0,
                                              float* __restrict__ out_h,
                                              float* __restrict__ out_c,
                                              unsigned* cnt) {
  __shared__ char smem[65536];           // h tile (swizzled), aliased by gbuf after use
  float* gbuf = (float*)smem;

  const int tid  = threadIdx.x;
  const int blk  = blockIdx.x;
  const int lane = tid & 63;
  const int w    = tid >> 6;
  const int g    = w >> 1;               // gate: 0=i 1=f 2=g 3=o
  const int mh   = w & 1;                // M half (batch rows 0-15 / 16-31)
  const int col  = lane & 15;
  const int kgrp = lane >> 4;
  const int n    = g * NH + blk * 16 + col;   // gate-matrix row
  const float bias_v = bias[n];
  const int arow = mh * 16 + col;        // A-fragment batch row
  const int axor = (arow & 7) << 4;
  const unsigned short* wrow = Wcat + (size_t)n * KT;

  const int pb = tid >> 4;               // pointwise: batch
  const int pj = tid & 15;               // pointwise: hidden-within-block
  const int hidx = blk * 16 + pj;
  float c_reg = c0[pb * NH + hidx];

  for (int t = 0; t < TT; ++t) {
    // stage h_t (bf16 [32][1024]) -> LDS with XOR swizzle
    const unsigned short* hsrc = hsx + (size_t)t * (BB * NH);
    #pragma unroll
    for (int it = 0; it < 8; ++it) {
      int ch = it * 512 + tid;               // 4096 chunks of 16B
      int row = ch >> 7;
      int boff = (ch & 127) << 4;
      s16x8 v = *(const s16x8*)(hsrc + ch * 8);
      *(s16x8*)(smem + row * 2048 + (boff ^ ((row & 7) << 4))) = v;
    }
    __syncthreads();

    f32x4 acc = {bias_v, bias_v, bias_v, bias_v};
    // x part: K 0..511 (A direct from global, per-lane row)
    const unsigned short* xrow = xe + ((size_t)t * BB + arow) * KX + kgrp * 8;
    const unsigned short* wx = wrow + kgrp * 8;
    #pragma unroll 4
    for (int k0 = 0; k0 < KX; k0 += 32) {
      s16x8 a = *(const s16x8*)(xrow + k0);
      s16x8 b = *(const s16x8*)(wx + k0);
      acc = __builtin_amdgcn_mfma_f32_16x16x32_bf16(a, b, acc, 0, 0, 0);
    }
    // h part: K 512..1535 (A from swizzled LDS)
    const char* hbase = smem + arow * 2048;
    const unsigned short* wh = wrow + KX + kgrp * 8;
    #pragma unroll 4
    for (int k0 = 0; k0 < NH; k0 += 32) {
      int boff = (k0 + kgrp * 8) << 1;
      s16x8 a = *(const s16x8*)(hbase + (boff ^ axor));
      s16x8 b = *(const s16x8*)(wh + k0);
      acc = __builtin_amdgcn_mfma_f32_16x16x32_bf16(a, b, acc, 0, 0, 0);
    }
    __syncthreads();  // done with h LDS; alias as gate buffer

    // D layout: row b = mh*16 + kgrp*4 + i, col = n-within-tile
    #pragma unroll
    for (int i = 0; i < 4; ++i) {
      int brow = mh * 16 + kgrp * 4 + i;
      gbuf[brow * 65 + col * 4 + g] = acc[i];
    }
    __syncthreads();

    // pointwise: one (b, j) per thread
    float gi = gbuf[pb * 65 + pj * 4 + 0];
    float gf = gbuf[pb * 65 + pj * 4 + 1];
    float gg = gbuf[pb * 65 + pj * 4 + 2];
    float go = gbuf[pb * 65 + pj * 4 + 3];
    float iv = 1.f / (1.f + __expf(-gi));
    float fv = 1.f / (1.f + __expf(-gf));
    float gv = tanhf(gg);
    float ov = 1.f / (1.f + __expf(-go));
    c_reg = fv * c_reg + iv * gv;
    float hv = ov * tanhf(c_reg);
    hsx[(size_t)(t + 1) * (BB * NH) + pb * NH + hidx] = f2bf(hv);
    if (t == TT - 1) {
      out_h[pb * NH + hidx] = hv;
      out_c[pb * NH + hidx] = c_reg;
    } else {
      grid_barrier(cnt, (unsigned)gridDim.x * (unsigned)(t + 1));
    }
  }
}

// ---------------- decoder GEMM: out[b][t][n] = hs[r]·Wb[n] + bd[n], r = t*32+b ----------------

__global__ __launch_bounds__(256) void k_dec(const unsigned short* __restrict__ A,  // [16384][1024]
                                             const unsigned short* __restrict__ Wb, // [N][1024]
                                             const float* __restrict__ bd,
                                             float* __restrict__ out, int N, int gn) {
  __shared__ char smem[32768];  // As [128][64] bf16 swizzled + Bs same at +16384
  const int tid = threadIdx.x;
  const int bid = blockIdx.x;
  const int tm = bid / gn, tn = bid % gn;
  const int lane = tid & 63;
  const int w = tid >> 6;
  const int wr = w >> 1, wc = w & 1;     // 2x2 wave grid, 64x64 subtile each
  const int col = lane & 15, kgrp = lane >> 4;

  f32x4 acc[4][4];
  #pragma unroll
  for (int i = 0; i < 4; ++i)
    #pragma unroll
    for (int j = 0; j < 4; ++j) acc[i][j] = {0.f, 0.f, 0.f, 0.f};

  const unsigned short* Ag = A + (size_t)(tm * 128) * NH;
  const unsigned short* Bg = Wb + (size_t)(tn * 128) * NH;

  for (int kb = 0; kb < 16; ++kb) {
    #pragma unroll
    for (int it = 0; it < 4; ++it) {
      int ch = it * 256 + tid;            // 1024 chunks of 16B each buffer
      int row = ch >> 3;
      int ko = (ch & 7) << 3;
      int lo = row * 128 + ((ko << 1) ^ ((row & 7) << 4));
      *(s16x8*)(smem + lo)         = *(const s16x8*)(Ag + (size_t)row * NH + kb * 64 + ko);
      *(s16x8*)(smem + 16384 + lo) = *(const s16x8*)(Bg + (size_t)row * NH + kb * 64 + ko);
    }
    __syncthreads();
    #pragma unroll
    for (int kk = 0; kk < 64; kk += 32) {
      s16x8 av[4], bv[4];
      #pragma unroll
      for (int mi = 0; mi < 4; ++mi) {
        int row = wr * 64 + mi * 16 + col;
        av[mi] = *(const s16x8*)(smem + row * 128 + (((kk + kgrp * 8) << 1) ^ ((row & 7) << 4)));
      }
      #pragma unroll
      for (int ni = 0; ni < 4; ++ni) {
        int row = wc * 64 + ni * 16 + col;
        bv[ni] = *(const s16x8*)(smem + 16384 + row * 128 + (((kk + kgrp * 8) << 1) ^ ((row & 7) << 4)));
      }
      #pragma unroll
      for (int mi = 0; mi < 4; ++mi)
        #pragma unroll
        for (int ni = 0; ni < 4; ++ni)
          acc[mi][ni] = __builtin_amdgcn_mfma_f32_16x16x32_bf16(av[mi], bv[ni], acc[mi][ni], 0, 0, 0);
    }
    __syncthreads();
  }

  #pragma unroll
  for (int ni = 0; ni < 4; ++ni) {
    int nn = tn * 128 + wc * 64 + ni * 16 + col;
    float bv = bd[nn];
    #pragma unroll
    for (int mi = 0; mi < 4; ++mi) {
      #pragma unroll
      for (int i = 0; i < 4; ++i) {
        int r = tm * 128 + wr * 64 + mi * 16 + kgrp * 4 + i;
        int t = r >> 5, b = r & 31;
        out[((size_t)b * TT + t) * N + nn] = acc[mi][ni][i] + bv;
      }
    }
  }
}

// ---------------- host ----------------

extern "C" void kernel_launch(void* const* d_in, const int* in_sizes, int n_in,
                              void* d_out, int out_size, void* d_ws, size_t ws_size,
                              hipStream_t stream) {
  const int*   tok0 = (const int*)d_in[0];
  const int*   tok1 = (const int*)d_in[1];
  const float* h0   = (const float*)d_in[2];
  const float* c0   = (const float*)d_in[3];
  const float* emb0 = (const float*)d_in[4];
  const float* emb1 = (const float*)d_in[5];
  const float* Wih  = (const float*)d_in[6];
  const float* Whh  = (const float*)d_in[7];
  const float* bih  = (const float*)d_in[8];
  const float* bhh  = (const float*)d_in[9];
  const float* Wd0  = (const float*)d_in[10];
  const float* bd0  = (const float*)d_in[11];
  const float* Wd1  = (const float*)d_in[12];
  const float* bd1  = (const float*)d_in[13];

  unsigned char* ws = (unsigned char*)d_ws;
  unsigned short* Wcat = (unsigned short*)(ws + WS_WCAT);
  unsigned short* Wd0b = (unsigned short*)(ws + WS_WD0);
  unsigned short* Wd1b = (unsigned short*)(ws + WS_WD1);
  unsigned short* xe   = (unsigned short*)(ws + WS_XE);
  unsigned short* hsx  = (unsigned short*)(ws + WS_HSX);
  float* bias = (float*)(ws + WS_BIAS);
  unsigned* cnt = (unsigned*)(ws + WS_CNT);
  float* out = (float*)d_out;

  k_wcat<<<NG, 256, 0, stream>>>(Wih, Whh, Wcat);
  k_wd<<<NT0 + NT1, 256, 0, stream>>>(Wd0, Wd1, Wd0b, Wd1b);
  k_misc<<<145, 256, 0, stream>>>(bih, bhh, h0, bias, hsx, cnt);
  k_embed<<<TT * BB, 64, 0, stream>>>(tok0, tok1, emb0, emb1, xe);
  k_lstm<<<64, 512, 0, stream>>>(xe, Wcat, bias, hsx, c0, out + OFF_H, out + OFF_C, cnt);
  k_dec<<<128 * 16, 256, 0, stream>>>(hsx + BB * NH, Wd0b, bd0, out, NT0, 16);
  k_dec<<<128 * 4, 256, 0, stream>>>(hsx + BB * NH, Wd1b, bd1, out + OFF_DEC1, NT1, 4);
}